// Round 11
// baseline (301.687 us; speedup 1.0000x reference)
//
#include <hip/hip_runtime.h>
#include <hip/hip_cooperative_groups.h>
#include <cmath>

#define D_ 128
#define H_ 256
#define W4 64                         // 4-elem groups per row (uint2 units)
#define PS (H_*W4)                    // plane stride in uint2 groups (16384)
#define NTOT (2*128*256*256)
#define GBLK 2048                     // b(2)*d(128)*h-eighth(8)
#define ROWS 8                        // rows per thread (upd path)
#define TSTART 6                      // first coop-tail iteration
#define STOPF 1e-4f

typedef _Float16 h4 __attribute__((ext_vector_type(4)));
typedef _Float16 h2v __attribute__((ext_vector_type(2)));

__device__ __forceinline__ float lk(float x){ return x >= 0.f ? x : 0.01f*x; }
__device__ __forceinline__ float4 ld4(const float4* p){ return *p; }
__device__ __forceinline__ float4 ld4(const h4* p){
    h4 v = *p; return make_float4((float)v.x,(float)v.y,(float)v.z,(float)v.w); }
__device__ __forceinline__ void st4(h4* p, float4 v){
    h4 r; r.x=(_Float16)v.x; r.y=(_Float16)v.y; r.z=(_Float16)v.z; r.w=(_Float16)v.w; *p = r; }
__device__ __forceinline__ float4 h4tof4(h4 v){
    return make_float4((float)v.x,(float)v.y,(float)v.z,(float)v.w); }
__device__ __forceinline__ h4 f4toh4(float4 v){
    h4 r; r.x=(_Float16)v.x; r.y=(_Float16)v.y; r.z=(_Float16)v.z; r.w=(_Float16)v.w; return r; }

// ---- packed fp16 helpers: v_pk_min/max_f16 (selection ops -> bit-exact) ----
#define PINF 0x7C007C00u
#define NINF 0xFC00FC00u
__device__ __forceinline__ uint32_t pmin(uint32_t a, uint32_t b){
    h2v r = __builtin_elementwise_min(__builtin_bit_cast(h2v,a), __builtin_bit_cast(h2v,b));
    return __builtin_bit_cast(uint32_t, r); }
__device__ __forceinline__ uint32_t pmax(uint32_t a, uint32_t b){
    h2v r = __builtin_elementwise_max(__builtin_bit_cast(h2v,a), __builtin_bit_cast(h2v,b));
    return __builtin_bit_cast(uint32_t, r); }
__device__ __forceinline__ uint2 pmin2(uint2 a, uint2 b){
    return make_uint2(pmin(a.x,b.x), pmin(a.y,b.y)); }
__device__ __forceinline__ uint2 pmax2(uint2 a, uint2 b){
    return make_uint2(pmax(a.x,b.x), pmax(a.y,b.y)); }
__device__ __forceinline__ float4 cvt4(uint32_t w01, uint32_t w23){
    h2v a = __builtin_bit_cast(h2v, w01);
    h2v b = __builtin_bit_cast(h2v, w23);
    return make_float4((float)a.x, (float)a.y, (float)b.x, (float)b.y); }
__device__ __forceinline__ uint2 pk4(float4 v){      // f32x4 -> packed fp16 (RTN)
    return __builtin_bit_cast(uint2, f4toh4(v)); }

// horizontal (w-axis) 3-window on packed pairs (4 elems / lane)
__device__ __forceinline__ uint2 hmin2(uint2 v, int lane){
    uint32_t pw = __shfl_up(v.y,1);   if (lane == 0)  pw = PINF;
    uint32_t nw = __shfl_down(v.x,1); if (lane == 63) nw = PINF;
    uint32_t l01 = (pw  >> 16) | (v.x << 16);
    uint32_t l23 = (v.x >> 16) | (v.y << 16);
    uint32_t r23 = (v.y >> 16) | (nw  << 16);
    return make_uint2(pmin(pmin(l01,v.x),l23), pmin(pmin(l23,v.y),r23));
}
__device__ __forceinline__ uint2 hmax2(uint2 v, int lane){
    uint32_t pw = __shfl_up(v.y,1);   if (lane == 0)  pw = NINF;
    uint32_t nw = __shfl_down(v.x,1); if (lane == 63) nw = NINF;
    uint32_t l01 = (pw  >> 16) | (v.x << 16);
    uint32_t l23 = (v.x >> 16) | (v.y << 16);
    uint32_t r23 = (v.y >> 16) | (nw  << 16);
    return make_uint2(pmax(pmax(l01,v.x),l23), pmax(pmax(l23,v.y),r23));
}

// geometry: block bi covers (b, d, h-eighth); wave owns ROWS rows.
// h-eighth in LOW 3 bits -> d-neighbor blocks (share X planes) on same XCD.
struct Geo { int lane, h0; size_t pbase; bool pm, pp; };
__device__ __forceinline__ Geo mkgeo(int tid, int bi){
    Geo g;
    g.lane = tid & 63;
    int wv = tid >> 6;
    int q = bi & 7, d = (bi >> 3) & 127, b = bi >> 10;
    g.h0 = q*32 + wv*ROWS;
    g.pbase = ((size_t)(b*128 + d))*PS + (size_t)g.lane;
    g.pm = (d > 0); g.pp = (d < 127);
    return g;
}

// ===================== init_k (verified x3) =================================
// R0 = erode(img0), R1 = erode(R0), S = leaky(img0 - dilate(R0)).
// fp16 rounding is monotone => fp16(min_f32(..)) == min_fp16(fp16(..)).
__global__ __launch_bounds__(256) void init_k(const float* __restrict__ img0,
                                              h4* __restrict__ R0,
                                              h4* __restrict__ R1,
                                              h4* __restrict__ Sb,
                                              int* __restrict__ frozen){
    if (blockIdx.x == 0 && threadIdx.x == 0) *frozen = 0;
    int tid = threadIdx.x, lane = tid & 63, wv = tid >> 6;
    int bi = blockIdx.x;
    int q = bi & 7, d = (bi >> 3) & 127, b = bi >> 10;
    int h0 = q*32 + wv*8;
    size_t pbase = ((size_t)(b*128 + d))*PS + (size_t)lane;
    bool dm1 = d >= 1, dm2 = d >= 2, dp1 = d <= 126, dp2 = d <= 125;
    const float4* Xc = (const float4*)img0 + pbase;
    uint2* E1w = (uint2*)R0 + pbase;
    uint2* E2w = (uint2*)R1 + pbase;
    h4*    Sw  = Sb + pbase;

    float4 rawC[4];
    uint2 mnA[4], mnB[4], mnC[4], mnE[4], mxE[4];

    auto ldmg = [&](int h, int sl){
        if (h >= 0 && h < H_){
            const float4* p = Xc + h*W4;
            float4 c4 = p[0]; rawC[sl] = c4;
            uint2 c = pk4(c4);
            uint2 xm1, xm2, xp1, xp2;
            if (dm1) xm1 = pk4(p[-(int)PS]);
            if (dm2) xm2 = pk4(p[-2*(int)PS]);
            if (dp1) xp1 = pk4(p[(int)PS]);
            if (dp2) xp2 = pk4(p[2*(int)PS]);
            uint2 mb = c;
            if (dm1) mb = pmin2(mb, xm1);
            if (dp1) mb = pmin2(mb, xp1);
            mnB[sl] = mb;
            if (dm1){ uint2 a = pmin2(xm1, c); if (dm2) a = pmin2(a, xm2); mnA[sl] = a; }
            if (dp1){ uint2 cc = pmin2(xp1, c); if (dp2) cc = pmin2(cc, xp2); mnC[sl] = cc; }
        } else {
            mnA[sl] = make_uint2(PINF,PINF); mnB[sl] = make_uint2(PINF,PINF);
            mnC[sl] = make_uint2(PINF,PINF);
            rawC[sl] = make_float4(0,0,0,0);
        }
    };
    auto e1row = [&](int e, int s0, int s1, int s2, int se, bool wr){
        if (e >= 0 && e < H_){
            uint2 vb = pmin2(mnB[s0], pmin2(mnB[s1], mnB[s2]));
            uint2 e1b = hmin2(vb, lane);
            uint2 mn = e1b, mx = e1b;
            if (dm1){
                uint2 va = pmin2(mnA[s0], pmin2(mnA[s1], mnA[s2]));
                uint2 e1a = hmin2(va, lane);
                mn = pmin2(mn, e1a); mx = pmax2(mx, e1a);
            }
            if (dp1){
                uint2 vc = pmin2(mnC[s0], pmin2(mnC[s1], mnC[s2]));
                uint2 e1c = hmin2(vc, lane);
                mn = pmin2(mn, e1c); mx = pmax2(mx, e1c);
            }
            mnE[se] = mn; mxE[se] = mx;
            if (wr) E1w[e*W4] = e1b;
        } else { mnE[se] = make_uint2(PINF,PINF); mxE[se] = make_uint2(NINF,NINF); }
    };

    ldmg(h0-2, 2); ldmg(h0-1, 3); ldmg(h0+0, 0); ldmg(h0+1, 1);
    e1row(h0-1, 2,3,0, 3, false);
    e1row(h0+0, 3,0,1, 0, true);
#pragma unroll
    for (int rr = 0; rr < 8; ++rr){
        int r = h0 + rr;
        ldmg(r+2, (rr+2)&3);
        e1row(r+1, rr&3, (rr+1)&3, (rr+2)&3, (rr+1)&3, rr < 7);
        uint2 v2 = pmin2(mnE[(rr+3)&3], pmin2(mnE[rr&3], mnE[(rr+1)&3]));
        E2w[r*W4] = hmin2(v2, lane);
        uint2 vv = pmax2(mxE[(rr+3)&3], pmax2(mxE[rr&3], mxE[(rr+1)&3]));
        uint2 ow = hmax2(vv, lane);
        float4 o = cvt4(ow.x, ow.y);
        float4 a = rawC[rr&3];
        float4 s0;
        s0.x = lk(a.x-o.x); s0.y = lk(a.y-o.y);
        s0.z = lk(a.z-o.z); s0.w = lk(a.w-o.w);
        st4(Sw + r*W4, s0);
    }
}

// ===================== round-6 4-slot packed core (verified best) ===========
// E = erode3(X) written out; O = dilate3(X) consumed inline. 4-slot X ring,
// distance-2 prefetch, 1-deep C/S prefetch. MODE 2: norm=|S_new|. 3: norm=|up|.
template<int MODE, int R>
__device__ __forceinline__ double phase_pk(
    const uint2* __restrict__ Xm, const uint2* __restrict__ Xc, const uint2* __restrict__ Xp,
    bool pm, bool pp,
    uint2* __restrict__ Ep, const h4* __restrict__ Cp, h4* __restrict__ Sp,
    float lr, int h0, int lane)
{
    uint2 rmn[4], rmx[4];
    double loc = 0.0;
    auto ldrow = [&](int j){
        int s = j & 3; int h = h0 - 1 + j;
        if (h >= 0 && h < H_){
            uint2 v = *(Xc + h*W4); uint2 mn = v, mx = v;
            if (pm){ uint2 u = *(Xm + h*W4); mn = pmin2(mn,u); mx = pmax2(mx,u); }
            if (pp){ uint2 u = *(Xp + h*W4); mn = pmin2(mn,u); mx = pmax2(mx,u); }
            rmn[s] = mn; rmx[s] = mx;
        } else {
            rmn[s] = make_uint2(PINF,PINF);
            rmx[s] = make_uint2(NINF,NINF);
        }
    };
    ldrow(0); ldrow(1); ldrow(2);
    float4 a_cur = ld4(Cp + h0*W4);
    float4 s_cur = ld4(Sp + h0*W4);
#pragma unroll
    for (int r = 0; r < R; ++r){
        if (r + 3 <= R + 1) ldrow(r+3);               // distance-2 prefetch
        float4 a_nxt = a_cur, s_nxt = s_cur;
        if (r + 1 < R){
            a_nxt = ld4(Cp + (h0+r+1)*W4);
            s_nxt = ld4(Sp + (h0+r+1)*W4);
        }
        uint2 vmn = pmin2(rmn[r&3], pmin2(rmn[(r+1)&3], rmn[(r+2)&3]));
        uint2 vmx = pmax2(rmx[r&3], pmax2(rmx[(r+1)&3], rmx[(r+2)&3]));
        uint2 ew = hmin2(vmn, lane);
        *(Ep + (h0+r)*W4) = ew;
        uint2 ow = hmax2(vmx, lane);
        float4 o = cvt4(ow.x, ow.y);
        float4 a = a_cur;
        float4 s = s_cur;
        float4 up; float dl;
        dl = lk(a.x-o.x); up.x = lk(dl - s.x*dl)*lr; s.x += up.x;
        dl = lk(a.y-o.y); up.y = lk(dl - s.y*dl)*lr; s.y += up.y;
        dl = lk(a.z-o.z); up.z = lk(dl - s.z*dl)*lr; s.z += up.z;
        dl = lk(a.w-o.w); up.w = lk(dl - s.w*dl)*lr; s.w += up.w;
        st4(Sp + (h0+r)*W4, s);
        if constexpr(MODE == 2)
            loc += (double)(fabsf(s.x)+fabsf(s.y)+fabsf(s.z)+fabsf(s.w));
        else
            loc += (double)(fabsf(up.x)+fabsf(up.y)+fabsf(up.z)+fabsf(up.w));
        a_cur = a_nxt; s_cur = s_nxt;
    }
    return loc;
}

// Update phase i. On freeze detection: writes out = 1.1*S inline.
template<int MODE>   // 2 (i==0, norm=|S|) or 3 (i>0, norm=|up|)
__global__ __launch_bounds__(256) void upd_k(const h4* __restrict__ Xb,
                                             const h4* __restrict__ Cb,
                                             h4* __restrict__ Eb,
                                             h4* __restrict__ Sb,
                                             const double* __restrict__ pr,
                                             double* __restrict__ pw,
                                             int* __restrict__ frozen,
                                             float* __restrict__ outp,
                                             float lr){
    if (*frozen) return;                       // cheap short-circuit after stop
    __shared__ double sm[4];
    int tid = threadIdx.x;
    int lane = tid & 63, wv = tid >> 6;
    if constexpr(MODE == 3){
        double v = 0.0;
#pragma unroll
        for (int j = 0; j < GBLK/256; ++j) v += pr[tid + 256*j];
#pragma unroll
        for (int o = 32; o; o >>= 1) v += __shfl_down(v, o);
        if (lane == 0) sm[wv] = v;
        __syncthreads();
        double tot = sm[0] + sm[1] + sm[2] + sm[3];
        if ((float)(tot / (double)NTOT) < STOPF){
            if (tid == 0) *frozen = 1;         // benign multi-block same-value write
            Geo g = mkgeo(tid, blockIdx.x);    // inline final scale: out = 1.1*S
            const h4* Sp = Sb + g.pbase;
            float4* O = (float4*)outp + g.pbase;
#pragma unroll
            for (int r = 0; r < ROWS; ++r){
                float4 s = h4tof4(Sp[(g.h0+r)*W4]);
                O[(g.h0+r)*W4] = make_float4(1.1f*s.x, 1.1f*s.y, 1.1f*s.z, 1.1f*s.w);
            }
            return;
        }
        __syncthreads();                       // protect sm reuse below
    }
    Geo g = mkgeo(tid, blockIdx.x);
    const uint2* Xc = (const uint2*)Xb + g.pbase;
    double loc = phase_pk<MODE,ROWS>(Xc-PS, Xc, Xc+PS, g.pm, g.pp,
                                     (uint2*)Eb + g.pbase, Cb + g.pbase, Sb + g.pbase,
                                     lr, g.h0, g.lane);
#pragma unroll
    for (int o = 32; o; o >>= 1) loc += __shfl_down(loc, o);
    if (lane == 0) sm[wv] = loc;
    __syncthreads();
    if (tid == 0) pw[blockIdx.x] = sm[0]+sm[1]+sm[2]+sm[3];
}

// Cooperative tail: iterations TSTART..19 + finalize. Common case (already
// frozen): read one flag and exit, replacing 14 frozen launches + scale.
__global__ __launch_bounds__(256) void tail_k(h4* __restrict__ rg0,
                                              h4* __restrict__ rg1,
                                              h4* __restrict__ rg2,
                                              h4* __restrict__ S,
                                              float* __restrict__ outp,
                                              const double* __restrict__ pr0,
                                              double* __restrict__ tp0,
                                              double* __restrict__ tp1,
                                              const int* __restrict__ frozen){
    if (*frozen) return;                       // scale already done at freeze
    cooperative_groups::grid_group gg = cooperative_groups::this_grid();
    __shared__ double sm[4];
    int tid = threadIdx.x, lane = tid & 63, wv = tid >> 6;
    int bi = blockIdx.x;
    int d = bi >> 3, b = (bi >> 2) & 1, q = bi & 3;   // 1024 blocks, 16 rows/thread
    int h0 = q*64 + wv*16;
    size_t pbase = ((size_t)(b*128 + d))*PS + (size_t)lane;
    bool pm = d > 0, pp = d < 127;
    const double* pr = pr0; int prn = GBLK;
    double* tpw = tp0;
    for (int i = TSTART; i < 20; ++i){
        double v = 0.0;
        for (int j = 0; j < prn/256; ++j) v += pr[tid + 256*j];
#pragma unroll
        for (int o = 32; o; o >>= 1) v += __shfl_down(v, o);
        if (lane == 0) sm[wv] = v;
        __syncthreads();
        double tot = sm[0] + sm[1] + sm[2] + sm[3];
        if ((float)(tot / (double)NTOT) < STOPF) break;
        __syncthreads();
        int xs = (i+1)%3, es = (i+2)%3, cs = i%3;
        h4* X = xs==0 ? rg0 : (xs==1 ? rg1 : rg2);
        h4* E = es==0 ? rg0 : (es==1 ? rg1 : rg2);
        h4* C = cs==0 ? rg0 : (cs==1 ? rg1 : rg2);
        float lr = 0.1f * exp2f(-(float)(i >> 2));
        const uint2* Xc = (const uint2*)X + pbase;
        double loc = phase_pk<3,16>(Xc-PS, Xc, Xc+PS, pm, pp, (uint2*)E + pbase,
                                    C + pbase, S + pbase, lr, h0, lane);
#pragma unroll
        for (int o = 32; o; o >>= 1) loc += __shfl_down(loc, o);
        if (lane == 0) sm[wv] = loc;
        __syncthreads();
        if (tid == 0) tpw[blockIdx.x] = sm[0]+sm[1]+sm[2]+sm[3];
        gg.sync();
        pr = tpw; prn = 1024;
        tpw = (tpw == tp0) ? tp1 : tp0;
    }
    const h4* Sp = S + pbase;
    float4* O = (float4*)outp + pbase;
#pragma unroll
    for (int r = 0; r < 16; ++r){
        float4 s = h4tof4(Sp[(h0+r)*W4]);
        O[(h0+r)*W4] = make_float4(1.1f*s.x, 1.1f*s.y, 1.1f*s.z, 1.1f*s.w);
    }
}

// Fallback-only standalone scale (dt == 0 identically -> out = 1.1*S)
__global__ __launch_bounds__(256) void scale_k(const h4* __restrict__ S,
                                               float* __restrict__ out){
    int t = blockIdx.x*256 + threadIdx.x;
#pragma unroll
    for (int c = 0; c < 4; ++c){
        int i = t + c*1048576;
        float4 s = ld4(S + i);
        float4 r = make_float4(1.1f*s.x, 1.1f*s.y, 1.1f*s.z, 1.1f*s.w);
        *(float4*)(out + (size_t)i*4) = r;
    }
}

extern "C" void kernel_launch(void* const* d_in, const int* in_sizes, int n_in,
                              void* d_out, int out_size, void* d_ws, size_t ws_size,
                              hipStream_t stream){
    const float* img0 = (const float*)d_in[0];
    float* out = (float*)d_out;
    char* ws = (char*)d_ws;
    size_t volh = (size_t)NTOT * 2;            // fp16 volume: 33.5 MB
    h4* ring[3] = { (h4*)ws, (h4*)(ws + volh), (h4*)(ws + 2*volh) };
    h4* S       = (h4*)(ws + 3*volh);
    double* parts[2] = { (double*)(ws + 4*volh), (double*)(ws + 4*volh) + GBLK };
    int* frozen = (int*)(ws + 4*volh + 2*GBLK*sizeof(double));
    double* tp0 = (double*)(ws + 4*volh + 2*GBLK*sizeof(double) + 256);
    double* tp1 = tp0 + 1024;

    dim3 blk(256), grd(GBLK);
    // fused init: R0 = erode(img0); R1 = erode(R0); S = leaky(img0 - open(img0))
    hipLaunchKernelGGL(init_k, grd, blk, 0, stream, img0, ring[0], ring[1], S, frozen);

    // iterations 0..TSTART-1 as plain dispatches (kernel boundary = cheap barrier)
    for (int i = 0; i < TSTART; ++i){
        h4* C = ring[i % 3];
        h4* X = ring[(i+1) % 3];
        h4* E = ring[(i+2) % 3];
        float lr = (float)(0.1 * pow(0.5, (double)(i / 4)));
        double* pw = parts[i & 1];
        double* pr = parts[1 - (i & 1)];
        if (i == 0)
            hipLaunchKernelGGL((upd_k<2>), grd, blk, 0, stream, X, C, E, S, pr, pw, frozen, out, lr);
        else
            hipLaunchKernelGGL((upd_k<3>), grd, blk, 0, stream, X, C, E, S, pr, pw, frozen, out, lr);
    }

    // coop tail: iterations TSTART..19 + finalize (fast exit when frozen)
    h4* a_r0 = ring[0]; h4* a_r1 = ring[1]; h4* a_r2 = ring[2];
    h4* a_S = S; float* a_out = out;
    const double* a_pr0 = parts[1 - (TSTART & 1)];   // partials from i=TSTART-1
    double* a_tp0 = tp0; double* a_tp1 = tp1; int* a_fz = frozen;
    void* args[9] = { &a_r0, &a_r1, &a_r2, &a_S, &a_out, &a_pr0, &a_tp0, &a_tp1, &a_fz };
    hipError_t ce = hipLaunchCooperativeKernel((const void*)tail_k, dim3(1024), blk,
                                               args, 0u, stream);
    if (ce != hipSuccess){
        // fallback: plain dispatches for the remaining iterations
        for (int i = TSTART; i < 20; ++i){
            h4* C = ring[i % 3];
            h4* X = ring[(i+1) % 3];
            h4* E = ring[(i+2) % 3];
            float lr = (float)(0.1 * pow(0.5, (double)(i / 4)));
            double* pw = parts[i & 1];
            double* pr = parts[1 - (i & 1)];
            hipLaunchKernelGGL((upd_k<3>), grd, blk, 0, stream, X, C, E, S, pr, pw, frozen, out, lr);
        }
        hipLaunchKernelGGL(scale_k, dim3(4096), blk, 0, stream, S, out);
    }
}